// Round 6
// baseline (810.917 us; speedup 1.0000x reference)
//
#include <hip/hip_runtime.h>

typedef unsigned int u32;
typedef unsigned short ushort_t;

// problem dims
#define NTOP 50
#define NT_T 50
#define NRHO 300
#define NVOC 20000
#define NTH 800
#define NEH 200
#define NSRC 10
#define NBAT 256

// ws offsets (float units), 32B aligned
#define OFF_SCAL     0          // 5 accumulators
#define OFF_MAPPED   16         // 500*200 fp32 (atomic)
#define OFF_HPRE     100016     // 256*800 fp32 (atomic)
#define OFF_H2       304816     // 256*800 fp32 (atomic)
#define OFF_Z        509616     // 2500 fp32 (atomic row-sums of E)
#define OFF_DOCCNT   512120     // 50 ints
#define OFF_DOCLIST  512176     // 50*256 ints
#define MEMSET_BYTES ((size_t)524976 * 4)
#define OFF_XW       524976     // 500*800 fp32
#define OFF_BIAS2    924976     // 800
#define OFF_ETAS     925776     // 10*50*50
#define OFF_WCOEF    950776     // 256*50
#define OFF_W1E      963576     // 800*50 compact W1[:,V:]
#define OFF_WHH_H    1003576    // 80000 u32 (f16 pairs) rows of 100
#define OFF_ETAWH    1083576    // 12800 u32 (f16 pairs) rows of 128
#define OFF_H1       1096376    // 256*800 fp32
#define OFF_ALPHAB   1301176    // bf16 [2560][320]
#define OFF_RHOB     1710776    // bf16 [20096][320]
#define OFF_LOGITH   4926136    // f16 E [2500][20000] = 12,500,000 f
// total ws: 17,426,136 floats = 69.7 MB

typedef _Float16 h2v __attribute__((ext_vector_type(2)));
typedef __bf16 bf16x8 __attribute__((ext_vector_type(8)));
typedef float f32x4 __attribute__((ext_vector_type(4)));

#define REP25(M) M(0) M(1) M(2) M(3) M(4) M(5) M(6) M(7) M(8) M(9) M(10) M(11) M(12) \
                 M(13) M(14) M(15) M(16) M(17) M(18) M(19) M(20) M(21) M(22) M(23) M(24)
#define REP7(M) M(0) M(1) M(2) M(3) M(4) M(5) M(6)

__device__ inline float dot2u(u32 a, u32 b, float c){
  h2v ha = __builtin_bit_cast(h2v, a), hb = __builtin_bit_cast(h2v, b);
#if __has_builtin(__builtin_amdgcn_fdot2)
  return __builtin_amdgcn_fdot2(ha, hb, c, false);
#else
  return c + (float)ha.x*(float)hb.x + (float)ha.y*(float)hb.y;
#endif
}

__device__ inline u32 packh2(float lo, float hi){
  h2v h; h.x = (_Float16)lo; h.y = (_Float16)hi;
  return __builtin_bit_cast(u32, h);
}

__device__ inline ushort_t f2bf(float f){
  u32 u = __builtin_bit_cast(u32, f);
  u = (u + 0x7FFFu + ((u >> 16) & 1u)) >> 16;
  return (ushort_t)u;
}

__device__ inline float fast_sig(float x){ return 1.f/(1.f + __expf(-x)); }
__device__ inline float fast_tanh(float x){ float e = __expf(2.f*x); return 1.f - 2.f/(e + 1.f); }

__device__ __forceinline__ void gl2lds16(const void* g, void* l){
  __builtin_amdgcn_global_load_lds((__attribute__((address_space(1))) void*)g,
                                   (__attribute__((address_space(3))) void*)l,
                                   16, 0, 0);
}

__device__ inline void blockReduceAdd(float v, float* red, float* target){
  int tid = threadIdx.x;
  red[tid] = v; __syncthreads();
  for (int o = blockDim.x >> 1; o > 0; o >>= 1){
    if (tid < o) red[tid] += red[tid + o];
    __syncthreads();
  }
  if (tid == 0) atomicAdd(target, red[0]);
}

// ---------------- device helper: fp32 -> bf16 padded convert ----------------
__device__ inline void conv_seg(const float* __restrict__ src, int ldsrc,
                                int Mreal, int Kused,
                                ushort_t* __restrict__ dst, int Kp, int idx)
{
  int kb = Kp >> 3;
  int row = idx / kb, c = (idx - row*kb) << 3;
  ushort_t out[8];
  #pragma unroll
  for (int j = 0; j < 8; j++){
    float v = 0.f;
    int k = c + j;
    if (row < Mreal && k < Kused) v = src[(size_t)row*ldsrc + k];
    out[j] = f2bf(v);
  }
  *(uint4*)(dst + (size_t)row*Kp + c) = *(uint4*)out;
}

// ---------------- mega prep/convert/klalpha kernel ----------------
// segments: [0,523) prep; [523,923) conva; [923,4063) rho; [4063,5087) klalpha
__global__ __launch_bounds__(256) void k_mega(
    const float* __restrict__ whh,
    const float* __restrict__ muEW, const float* __restrict__ lsEW,
    const float* __restrict__ bih, const float* __restrict__ bhh,
    const float* __restrict__ wih, const float* __restrict__ emapB,
    const float* __restrict__ W1, const int* __restrict__ times,
    const float* __restrict__ muq, const float* __restrict__ lsq,
    const float* __restrict__ rho, float* __restrict__ W)
{
  int b = blockIdx.x, tid = threadIdx.x;
  __shared__ float red[256];
  if (b < 523){
    int idx = b*256 + tid;
    u32* whhH = (u32*)(W + OFF_WHH_H);
    u32* etaWH = (u32*)(W + OFF_ETAWH);
    if (idx < 80000){
      int j = idx/100; int i = idx - j*100;
      whhH[idx] = packh2(whh[j*200 + 2*i], whh[j*200 + 2*i + 1]);
    } else if (idx < 92800){
      int d = idx - 80000; int q = d >> 7; int i = d & 127;
      u32 v = 0u;
      if (i < 125){
        const float* src = (q < 50) ? (muEW + q*250) : (lsEW + (q-50)*250);
        v = packh2(src[2*i], src[2*i+1]);
      }
      etaWH[d] = v;
    } else if (idx < 93600){
      int j = idx - 92800;
      float acc = bih[j] + bhh[j];
      const float* wr = wih + (size_t)j*200;
      #pragma unroll 4
      for (int k = 0; k < 200; k++) acc += emapB[k]*wr[k];
      W[OFF_BIAS2 + j] = acc;
    } else if (idx < 133600){
      int d = idx - 93600; int j = d/50; int k = d - j*50;
      W[OFF_W1E + d] = W1[(size_t)j*20050 + 20000 + k];
    } else if (idx < 133856){
      int bb = idx - 133600; int t = times[bb];
      int* docCnt = (int*)(W + OFF_DOCCNT);
      int* docList = (int*)(W + OFF_DOCLIST);
      int pos = atomicAdd(&docCnt[t], 1);
      docList[t*256 + pos] = bb;
    }
  } else if (b < 923){
    // alphas permute+pad: dst[t*50+k][r] = muq[k][t][r]
    int idx = (b-523)*256 + tid;
    int row = idx / 40, c = (idx - row*40) << 3;
    ushort_t out[8];
    const float* src = nullptr;
    if (row < 2500){ int t = row/50, k = row - t*50; src = muq + (size_t)k*15000 + t*300; }
    #pragma unroll
    for (int j = 0; j < 8; j++){
      int r = c + j;
      float v = (src && r < 300) ? src[r] : 0.f;
      out[j] = f2bf(v);
    }
    *(uint4*)((ushort_t*)(W + OFF_ALPHAB) + (size_t)row*320 + c) = *(uint4*)out;
  } else if (b < 4063){
    conv_seg(rho, 300, 20000, 300, (ushort_t*)(W + OFF_RHOB), 320, (b-923)*256 + tid);
  } else {
    // kl_alpha
    const float inv_dl = 1.f/(0.005f + 1e-6f);
    const float logdl = -5.2983173665480363f;
    float local = 0.f;
    for (int idx = (b-4063)*256 + tid; idx < 750000; idx += 1024*256){
      int rem = idx % 15000; int t = rem / 300;
      float ls = lsq[idx]; float mu = muq[idx];
      if (t == 0){
        local += 0.5f*((__expf(ls) + mu*mu)/(1.f + 1e-6f) - 1.f - ls);
      } else {
        float d = mu - muq[idx - 300];
        local += 0.5f*((__expf(ls) + d*d)*inv_dl - 1.f + logdl - ls);
      }
    }
    blockReduceAdd(local, red, W + OFF_SCAL + 1);
  }
}

// ---------------- fp32 staging helper: load 8 floats, cvt bf16, ds_write_b128 ----------------
__device__ __forceinline__ void stage_f32(
    const float* __restrict__ src, int ld, int gRow, int rowMax,
    int k0, int Kreal, ushort_t* __restrict__ dst)
{
  u32 pk[4];
  const float* p = src + (size_t)gRow*ld + k0;
  bool rowOK = gRow < rowMax;
  if (rowOK && (k0 + 7 < Kreal)){
    float2 f0 = *(const float2*)(p);
    float2 f1 = *(const float2*)(p + 2);
    float2 f2 = *(const float2*)(p + 4);
    float2 f3 = *(const float2*)(p + 6);
    pk[0] = (u32)f2bf(f0.x) | ((u32)f2bf(f0.y) << 16);
    pk[1] = (u32)f2bf(f1.x) | ((u32)f2bf(f1.y) << 16);
    pk[2] = (u32)f2bf(f2.x) | ((u32)f2bf(f2.y) << 16);
    pk[3] = (u32)f2bf(f3.x) | ((u32)f2bf(f3.y) << 16);
  } else {
    #pragma unroll
    for (int ii = 0; ii < 4; ii++){
      int k = k0 + ii*2;
      float x = (rowOK && k   < Kreal) ? p[ii*2]   : 0.f;
      float y = (rowOK && k+1 < Kreal) ? p[ii*2+1] : 0.f;
      pk[ii] = (u32)f2bf(x) | ((u32)f2bf(y) << 16);
    }
  }
  *(uint4*)dst = *(uint4*)pk;
}

// ---------------- bf16 MFMA NT GEMM with in-kernel fp32->bf16 staging ----------------
// C[M,N] = A[M,K] . B[N,K]^T, A/B fp32 row-major. LDS rows padded to 40 ushorts
// (conflict-free; no global_load_lds so padding is allowed).
// MODE 0: atomic f32 epilogue; MODE 2: f32 store + col-bias.
#define LDP 40
template<int MODE>
__global__ __launch_bounds__(256) void mfma_ntf(
    const float* __restrict__ A, int lda,
    const float* __restrict__ B, int ldb,
    float* __restrict__ C, int ldc, const float* __restrict__ nBias,
    int M, int N, int Kreal, int mT, int kS, int chunks)
{
  __shared__ __align__(16) ushort_t As[128*LDP];
  __shared__ __align__(16) ushort_t Bs[128*LDP];
  int bid = blockIdx.x;
  int kIdx = bid % kS; int rest = bid / kS;
  int mIdx = rest % mT; int nIdx = rest / mT;
  int tid = threadIdx.x;
  int w = tid >> 6, l = tid & 63;
  int c0 = (chunks * kIdx) / kS;
  int c1 = (chunks * (kIdx+1)) / kS;
  int r0 = w*32;
  int row16 = l >> 2, kq = (l & 3) * 8;
  int wr = (w >> 1)*64, wc = (w & 1)*64;
  int lr = l & 15, lq = l >> 4;
  f32x4 acc[4][4];
  #pragma unroll
  for (int i = 0; i < 4; i++)
    #pragma unroll
    for (int j = 0; j < 4; j++)
      acc[i][j] = (f32x4)0.f;

  for (int c = c0; c < c1; c++){
    int k0 = c*32 + kq;
    stage_f32(A, lda, mIdx*128 + r0 +      row16, M, k0, Kreal, As + (r0 +      row16)*LDP + kq);
    stage_f32(A, lda, mIdx*128 + r0 + 16 + row16, M, k0, Kreal, As + (r0 + 16 + row16)*LDP + kq);
    stage_f32(B, ldb, nIdx*128 + r0 +      row16, N, k0, Kreal, Bs + (r0 +      row16)*LDP + kq);
    stage_f32(B, ldb, nIdx*128 + r0 + 16 + row16, N, k0, Kreal, Bs + (r0 + 16 + row16)*LDP + kq);
    __syncthreads();
    bf16x8 av[4], bv[4];
    #pragma unroll
    for (int i = 0; i < 4; i++)
      av[i] = *(const bf16x8*)(As + (wr + i*16 + lr)*LDP + lq*8);
    #pragma unroll
    for (int j = 0; j < 4; j++)
      bv[j] = *(const bf16x8*)(Bs + (wc + j*16 + lr)*LDP + lq*8);
    #pragma unroll
    for (int i = 0; i < 4; i++)
      #pragma unroll
      for (int j = 0; j < 4; j++)
        acc[i][j] = __builtin_amdgcn_mfma_f32_16x16x32_bf16(av[i], bv[j], acc[i][j], 0, 0, 0);
    __syncthreads();
  }
  #pragma unroll
  for (int i = 0; i < 4; i++){
    #pragma unroll
    for (int r = 0; r < 4; r++){
      int row = mIdx*128 + wr + i*16 + lq*4 + r;
      if (row >= M) continue;
      #pragma unroll
      for (int j = 0; j < 4; j++){
        int col = nIdx*128 + wc + j*16 + lr;
        if (col >= N) continue;
        float v = acc[i][j][r];
        if (MODE == 0) atomicAdd(&C[(size_t)row*ldc + col], v);
        else           C[(size_t)row*ldc + col] = v + nBias[col];
      }
    }
  }
}

// ---------------- E = exp(alpha @ rho^T) GEMM: A from global regs, coalesced epilogue ----
// M=2500 (mT=20 m-tiles, mIdx fastest for B-tile L2 reuse), N=20000 (157 n-tiles), K=320.
__global__ __launch_bounds__(256) void mfma_e(
    const ushort_t* __restrict__ A,   // alphaB [2560][320]
    const ushort_t* __restrict__ B,   // rhoB [20096][320]
    float* __restrict__ Z, _Float16* __restrict__ E)
{
  __shared__ __align__(16) ushort_t Bs[128*32];     // 8 KB
  __shared__ __align__(16) _Float16 Eb[64*136];     // 17 KB bounce (stride 136)
  int bid = blockIdx.x;
  int mIdx = bid % 20, nIdx = bid / 20;
  int tid = threadIdx.x;
  int w = tid >> 6, l = tid & 63;
  int r0 = w*32;
  const ushort_t* gb0 = B + (size_t)(nIdx*128 + r0      + (l>>2))*320 + (l&3)*8;
  const ushort_t* gb1 = B + (size_t)(nIdx*128 + r0 + 16 + (l>>2))*320 + (l&3)*8;
  ushort_t* lb = Bs + r0*32;
  int wr = (w >> 1)*64, wc = (w & 1)*64;
  int lr = l & 15, lq = l >> 4;
  int aRow[4];
  #pragma unroll
  for (int i = 0; i < 4; i++) aRow[i] = mIdx*128 + wr + i*16 + lr;
  f32x4 acc[4][4];
  #pragma unroll
  for (int i = 0; i < 4; i++)
    #pragma unroll
    for (int j = 0; j < 4; j++)
      acc[i][j] = (f32x4)0.f;

  bf16x8 avn[4];
  #pragma unroll
  for (int i = 0; i < 4; i++)
    avn[i] = *(const bf16x8*)(A + (size_t)aRow[i]*320 + lq*8);

  for (int c = 0; c < 10; c++){
    gl2lds16(gb0 + c*32, lb);
    gl2lds16(gb1 + c*32, lb + 512);
    bf16x8 av[4];
    #pragma unroll
    for (int i = 0; i < 4; i++) av[i] = avn[i];
    if (c < 9){
      #pragma unroll
      for (int i = 0; i < 4; i++)
        avn[i] = *(const bf16x8*)(A + (size_t)aRow[i]*320 + (c+1)*32 + lq*8);
    }
    __syncthreads();
    bf16x8 bv[4];
    #pragma unroll
    for (int j = 0; j < 4; j++)
      bv[j] = *(const bf16x8*)(Bs + (wc + j*16 + lr)*32 + lq*8);
    #pragma unroll
    for (int i = 0; i < 4; i++)
      #pragma unroll
      for (int j = 0; j < 4; j++)
        acc[i][j] = __builtin_amdgcn_mfma_f32_16x16x32_bf16(av[i], bv[j], acc[i][j], 0, 0, 0);
    __syncthreads();
  }
  // epilogue: exp + Z row-sums + LDS bounce -> coalesced dwordx4 stores, 2 halves of 64 rows
  int half = w >> 1;
  for (int h = 0; h < 2; h++){
    if (half == h){
      #pragma unroll
      for (int i = 0; i < 4; i++){
        #pragma unroll
        for (int r = 0; r < 4; r++){
          int lrow = i*16 + lq*4 + r;
          int grow = mIdx*128 + h*64 + lrow;
          float p = 0.f;
          #pragma unroll
          for (int j = 0; j < 4; j++){
            int col = nIdx*128 + wc + j*16 + lr;
            float e = (col < NVOC) ? __expf(acc[i][j][r]) : 0.f;
            Eb[lrow*136 + wc + j*16 + lr] = (_Float16)e;
            p += e;
          }
          p += __shfl_xor(p, 1, 16);
          p += __shfl_xor(p, 2, 16);
          p += __shfl_xor(p, 4, 16);
          p += __shfl_xor(p, 8, 16);
          if (lr == 0 && grow < 2500) atomicAdd(&Z[grow], p);
        }
      }
    }
    __syncthreads();
    int lrow = tid >> 2, coff = (tid & 3) * 32;
    int grow = mIdx*128 + h*64 + lrow;
    if (grow < 2500){
      int gcol0 = nIdx*128 + coff;
      if (gcol0 + 31 < NVOC){
        #pragma unroll
        for (int cc = 0; cc < 4; cc++)
          *(uint4*)(E + (size_t)grow*NVOC + gcol0 + cc*8) = *(uint4*)(Eb + lrow*136 + coff + cc*8);
      } else {
        for (int cc = 0; cc < 32; cc++){
          int gc = gcol0 + cc;
          if (gc < NVOC) E[(size_t)grow*NVOC + gc] = Eb[lrow*136 + coff + cc];
        }
      }
    }
    __syncthreads();
  }
}

// ---------------- fused LSTM + eta recurrence, one block per source ----------------
__global__ __launch_bounds__(512, 2) void k_lstm(
    const float* __restrict__ xw, const u32* __restrict__ whhH, const uint4* __restrict__ etaW4,
    const float* __restrict__ muEB, const float* __restrict__ lsEB,
    float* __restrict__ etas, float* __restrict__ W)
{
  int s = blockIdx.x; int tid = threadIdx.x;
  __shared__ uint4 hp4[2][32];
  __shared__ float zbuf[800];
  __shared__ float red[512];
  uint4 z4; z4.x = z4.y = z4.z = z4.w = 0u;
#define DECLW(i) uint4 wa##i = z4, wb##i = z4;
  REP25(DECLW)
#undef DECLW
  float ebias = 0.f;
  if (tid < 400){
    const uint4* ra = (const uint4*)(whhH + tid*100);
    const uint4* rb = (const uint4*)(whhH + (tid + 400)*100);
#define LDW(i) wa##i = ra[i]; wb##i = rb[i];
    REP25(LDW)
#undef LDW
  } else if (tid < 500){
    int q = tid - 400;
    const uint4* re = etaW4 + q*32;
#define LDA(i) wa##i = re[i];
    REP25(LDA)
#undef LDA
#define LDB(i) wb##i = re[25+i];
    REP7(LDB)
#undef LDB
    ebias = (q < 50) ? muEB[q] : lsEB[q - 50];
  }
  float creg = 0.f, muPrev = 0.f, klLocal = 0.f;
  if (tid < 64) ((uint4*)hp4)[tid] = z4;
  __syncthreads();
  const float inv_dl = 1.f/(0.005f + 1e-6f);
  const float logdl = -5.2983173665480363f;

  for (int t = 0; t < NT_T; t++){
    const uint4* hc = hp4[t & 1];
    uint4* hn = hp4[(t + 1) & 1];
    if (tid < 400){
      float a0=0.f,a1=0.f,a2=0.f,a3=0.f,b0=0.f,b1=0.f,b2=0.f,b3=0.f;
#define DOT(i) { uint4 h = hc[i]; \
      a0 = dot2u(wa##i.x, h.x, a0); a1 = dot2u(wa##i.y, h.y, a1); \
      a2 = dot2u(wa##i.z, h.z, a2); a3 = dot2u(wa##i.w, h.w, a3); \
      b0 = dot2u(wb##i.x, h.x, b0); b1 = dot2u(wb##i.y, h.y, b1); \
      b2 = dot2u(wb##i.z, h.z, b2); b3 = dot2u(wb##i.w, h.w, b3); }
      REP25(DOT)
#undef DOT
      const float* xr = xw + (size_t)(s*50 + t)*800;
      zbuf[tid]       = ((a0+a1)+(a2+a3)) + xr[tid];
      zbuf[tid + 400] = ((b0+b1)+(b2+b3)) + xr[tid + 400];
    }
    __syncthreads();  // B1
    if (tid < 200){
      float zi = zbuf[tid], zf = zbuf[200+tid], zg = zbuf[400+tid], zo = zbuf[600+tid];
      float ig = fast_sig(zi);
      float fg = fast_sig(zf);
      float gg = fast_tanh(zg);
      float og = fast_sig(zo);
      creg = fg*creg + ig*gg;
      float hv = og*fast_tanh(creg);
      ((_Float16*)hn)[tid] = (_Float16)hv;
    }
    __syncthreads();  // B2
    if (tid >= 400 && tid < 500){
      float e0 = ebias, e1 = 0.f, e2 = 0.f, e3 = 0.f;
#define DOTE(i) { uint4 h = hn[i]; \
      e0 = dot2u(wa##i.x, h.x, e0); e1 = dot2u(wa##i.y, h.y, e1); \
      e2 = dot2u(wa##i.z, h.z, e2); e3 = dot2u(wa##i.w, h.w, e3); }
      REP25(DOTE)
#undef DOTE
#define DOTP(i) { uint4 h = hc[25+i]; \
      e0 = dot2u(wb##i.x, h.x, e0); e1 = dot2u(wb##i.y, h.y, e1); \
      e2 = dot2u(wb##i.z, h.z, e2); e3 = dot2u(wb##i.w, h.w, e3); }
      REP7(DOTP)
#undef DOTP
      float eacc = (e0+e1)+(e2+e3);
      int q = tid - 400;
      if (q < 50){
        float mu = eacc;
        etas[(size_t)(s*50 + t)*50 + q] = mu;
        if (t == 0) klLocal += 0.5f*mu*mu/(1.f + 1e-6f);
        else { float d = mu - muPrev; klLocal += 0.5f*d*d*inv_dl; }
        muPrev = mu;
        ((_Float16*)hn)[200 + q] = (_Float16)mu;
      } else {
        float ls = eacc;
        if (t == 0) klLocal += 0.5f*(__expf(ls)/(1.f + 1e-6f) - 1.f - ls);
        else {
          ls = fminf(fmaxf(ls, -10.f), 10.f);
          klLocal += 0.5f*(__expf(ls)*inv_dl - 1.f + logdl - ls);
        }
      }
    }
  }
  __syncthreads();
  blockReduceAdd(klLocal, red, W + OFF_SCAL + 2);
}

// ---------------- h1 = relu(hpre + b1 + eta_std @ W1E^T) -> fp32 ----------------
__global__ __launch_bounds__(256) void k_h1(
    const float* __restrict__ hpre, const float* __restrict__ b1, const float* __restrict__ w1e,
    const float* __restrict__ etas, const int* __restrict__ times, const int* __restrict__ srcs,
    float* __restrict__ h1)
{
  int b = blockIdx.x, tid = threadIdx.x;
  __shared__ float et[50];
  int tb = times[b], sb = srcs[b];
  if (tid < 50) et[tid] = etas[(size_t)(sb*50 + tb)*50 + tid];
  __syncthreads();
  for (int j = tid; j < 800; j += 256){
    float acc = hpre[(size_t)b*800 + j] + b1[j];
    const float* wrow = w1e + (size_t)j*50;
    #pragma unroll
    for (int k = 0; k < 50; k++) acc += et[k]*wrow[k];
    h1[(size_t)b*800 + j] = fmaxf(acc, 0.f);
  }
}

// ---------------- theta head ----------------
__global__ __launch_bounds__(256) void k_thfin(
    const float* __restrict__ h2g, const float* __restrict__ b2, const float* __restrict__ etas,
    const int* __restrict__ times, const int* __restrict__ srcs,
    const float* __restrict__ muW, const float* __restrict__ muB,
    const float* __restrict__ lsW, const float* __restrict__ lsB,
    const float* __restrict__ clsW, const float* __restrict__ clsB,
    const float* __restrict__ Zrow, float* __restrict__ wcoef, float* __restrict__ W)
{
  int b = blockIdx.x, tid = threadIdx.x;
  __shared__ float h2s[800], mu[50], lsv[50], et[50], th[50], lg[10], red[64], shm[2];
  for (int j = tid; j < 800; j += 256) h2s[j] = fmaxf(h2g[(size_t)b*800 + j] + b2[j], 0.f);
  int tb = times[b], sb = srcs[b];
  if (tid < 50) et[tid] = etas[(size_t)(sb*50 + tb)*50 + tid];
  __syncthreads();
  if (tid < 100){
    int q = (tid < 50) ? tid : tid - 50;
    const float* w = (tid < 50) ? (muW + (size_t)q*800) : (lsW + (size_t)q*800);
    float acc = (tid < 50) ? muB[q] : lsB[q];
    #pragma unroll 8
    for (int j = 0; j < 800; j++) acc += h2s[j]*w[j];
    if (tid < 50) mu[q] = acc;
    else lsv[q] = fminf(fmaxf(acc, -10.f), 10.f);
  }
  __syncthreads();
  if (tid == 0){ float m = -1e30f; for (int k = 0; k < 50; k++) m = fmaxf(m, mu[k]); shm[0] = m; }
  __syncthreads();
  if (tid < 50) th[tid] = __expf(mu[tid] - shm[0]);
  __syncthreads();
  if (tid == 0){ float z = 0.f; for (int k = 0; k < 50; k++) z += th[k]; shm[1] = z; }
  __syncthreads();
  if (tid < 64) red[tid] = 0.f;
  if (tid < 50){
    float t_ = th[tid]/shm[1]; th[tid] = t_;
    wcoef[(size_t)b*50 + tid] = t_/Zrow[tb*50 + tid];
    float d = mu[tid] - et[tid];
    red[tid] = 0.5f*((__expf(lsv[tid]) + d*d)/(1.f + 1e-6f) - 1.f - lsv[tid]);
  }
  __syncthreads();
  if (tid < 10){
    float a = clsB[tid];
    #pragma unroll
    for (int k = 0; k < 50; k++) a += th[k]*clsW[tid*50 + k];
    lg[tid] = a;
  }
  __syncthreads();
  if (tid == 0){
    float m = -1e30f; for (int i = 0; i < 10; i++) m = fmaxf(m, lg[i]);
    float z = 0.f; for (int i = 0; i < 10; i++) z += __expf(lg[i] - m);
    float lse = m + __logf(z);
    atomicAdd(W + OFF_SCAL + 4, lse - lg[sb]);
    float ssum = 0.f; for (int i = 0; i < 50; i++) ssum += red[i];
    atomicAdd(W + OFF_SCAL + 3, ssum);
  }
}

// ---------------- nll: 2 vocab entries per thread ----------------
__global__ __launch_bounds__(256) void k_nll(
    const _Float16* __restrict__ E, const float* __restrict__ wcoef,
    const float* __restrict__ bows, float* __restrict__ W)
{
  int t = blockIdx.x/10, vc = blockIdx.x%10;
  int v0 = vc*2000;
  int tid = threadIdx.x;
  const int* docCnt = (const int*)(W + OFF_DOCCNT);
  const int* docList = (const int*)(W + OFF_DOCLIST);
  __shared__ float wch[64*50];
  __shared__ int ids[64];
  __shared__ float red[256];
  int nd = docCnt[t];
  float acc = 0.f;
  for (int d0 = 0; d0 < nd; d0 += 64){
    int ndc = min(64, nd - d0);
    __syncthreads();
    for (int i = tid; i < ndc*50; i += 256){
      int d = i/50, k = i - d*50;
      int bb = docList[t*256 + d0 + d];
      if (k == 0) ids[d] = bb;
      wch[i] = wcoef[(size_t)bb*50 + k];
    }
    __syncthreads();
    for (int v = v0 + tid*2; v < v0 + 2000; v += 512){
      float ex[50], ey[50];
      #pragma unroll
      for (int k = 0; k < 50; k++){
        u32 pk = *(const u32*)(E + (size_t)(t*50 + k)*NVOC + v);
        h2v h = __builtin_bit_cast(h2v, pk);
        ex[k] = (float)h.x; ey[k] = (float)h.y;
      }
      for (int d = 0; d < ndc; d++){
        float sx = 0.f, sy = 0.f;
        #pragma unroll
        for (int k = 0; k < 50; k++){
          float wv = wch[d*50 + k];
          sx += wv*ex[k]; sy += wv*ey[k];
        }
        float2 bw = *(const float2*)(bows + (size_t)ids[d]*NVOC + v);
        acc += bw.x*__logf(sx) + bw.y*__logf(sy);
      }
    }
  }
  __syncthreads();
  blockReduceAdd(acc, red, W + OFF_SCAL + 0);
}

// ---------------- finalize ----------------
__global__ void k_final(const float* __restrict__ W, const int* __restrict__ ndocs, float* __restrict__ out)
{
  if (blockIdx.x == 0 && threadIdx.x == 0){
    float coeff = (float)ndocs[0] / 256.f;
    const float* scal = W + OFF_SCAL;
    float nll  = -scal[0]*coeff;
    float kla  = scal[1];
    float kle  = scal[2];
    float klth = scal[3]*coeff;
    float pred = scal[4]*coeff;
    out[0] = nll + kla + kle + klth + pred;
    out[1] = nll; out[2] = kla; out[3] = kle; out[4] = klth; out[5] = pred;
  }
}

extern "C" void kernel_launch(void* const* d_in, const int* in_sizes, int n_in,
                              void* d_out, int out_size, void* d_ws, size_t ws_size,
                              hipStream_t stream)
{
  (void)in_sizes; (void)n_in; (void)out_size; (void)ws_size;
  const float* bows  = (const float*)d_in[1];
  const float* nb    = (const float*)d_in[2];
  const int*   times = (const int*)d_in[3];
  const int*   srcs  = (const int*)d_in[4];
  const float* rnn   = (const float*)d_in[5];
  const int*   ndocs = (const int*)d_in[6];
  const float* muq   = (const float*)d_in[7];
  const float* lsq   = (const float*)d_in[8];
  const float* rho   = (const float*)d_in[9];
  const float* W1    = (const float*)d_in[10];
  const float* b1    = (const float*)d_in[11];
  const float* W2    = (const float*)d_in[12];
  const float* b2    = (const float*)d_in[13];
  const float* muthW = (const float*)d_in[14];
  const float* muthB = (const float*)d_in[15];
  const float* lsthW = (const float*)d_in[16];
  const float* lsthB = (const float*)d_in[17];
  const float* emapW = (const float*)d_in[18];
  const float* emapB = (const float*)d_in[19];
  const float* wih   = (const float*)d_in[20];
  const float* whh   = (const float*)d_in[21];
  const float* bih   = (const float*)d_in[22];
  const float* bhh   = (const float*)d_in[23];
  const float* muEW  = (const float*)d_in[24];
  const float* muEB  = (const float*)d_in[25];
  const float* lsEW  = (const float*)d_in[26];
  const float* lsEB  = (const float*)d_in[27];
  const float* clsW  = (const float*)d_in[28];
  const float* clsB  = (const float*)d_in[29];

  float* W = (float*)d_ws;
  ushort_t* alphaB = (ushort_t*)(W + OFF_ALPHAB);
  ushort_t* rhoB   = (ushort_t*)(W + OFF_RHOB);
  _Float16* Ehalf  = (_Float16*)(W + OFF_LOGITH);

  hipMemsetAsync(d_ws, 0, MEMSET_BYTES, stream);

  // prep + alpha/rho bf16 conversions + kl_alpha
  k_mega<<<5087, 256, 0, stream>>>(whh, muEW, lsEW, bih, bhh, wih, emapB, W1, times,
                                   muq, lsq, rho, W);

  // E = exp(alphasT @ rho^T) -> f16 + row-sums Z   M=2500 N=20000 K=320
  mfma_e<<<20*157, 256, 0, stream>>>(alphaB, rhoB, W + OFF_Z, Ehalf);

  // mapped = rnn @ eta_map_W^T  M=500 N=200 K=20000  (fp32 in, split-K atomic)
  mfma_ntf<0><<<4*2*32, 256, 0, stream>>>(
      rnn, 20000, emapW, 20000, W + OFF_MAPPED, 200, nullptr,
      500, 200, 20000, 4, 32, 625);

  // xw = mapped @ wih^T + bias2  M=500 N=800 K=200 (fp32 in)
  mfma_ntf<2><<<4*7, 256, 0, stream>>>(
      W + OFF_MAPPED, 200, wih, 200, W + OFF_XW, 800, W + OFF_BIAS2,
      500, 800, 200, 4, 1, 7);

  k_lstm<<<NSRC, 512, 0, stream>>>(W + OFF_XW, (const u32*)(W + OFF_WHH_H),
                                   (const uint4*)(W + OFF_ETAWH), muEB, lsEB,
                                   W + OFF_ETAS, W);

  // hpre = nb @ W1[:, :V]^T  M=256 N=800 K=20000 (fp32 in, ldb=20050, split-K atomic)
  mfma_ntf<0><<<2*7*20, 256, 0, stream>>>(
      nb, 20000, W1, 20050, W + OFF_HPRE, 800, nullptr,
      256, 800, 20000, 2, 20, 625);

  k_h1<<<256, 256, 0, stream>>>(W + OFF_HPRE, b1, W + OFF_W1E, W + OFF_ETAS, times, srcs,
                                W + OFF_H1);

  // h2pre = h1 @ W2^T  M=256 N=800 K=800 (fp32 in, split-K atomic)
  mfma_ntf<0><<<2*7*2, 256, 0, stream>>>(
      W + OFF_H1, 800, W2, 800, W + OFF_H2, 800, nullptr,
      256, 800, 800, 2, 2, 25);

  k_thfin<<<256, 256, 0, stream>>>(W + OFF_H2, b2, W + OFF_ETAS, times, srcs,
                                   muthW, muthB, lsthW, lsthB, clsW, clsB,
                                   W + OFF_Z, W + OFF_WCOEF, W);

  k_nll<<<500, 256, 0, stream>>>(Ehalf, W + OFF_WCOEF, bows, W);

  k_final<<<1, 64, 0, stream>>>(W, ndocs, (float*)d_out);
}